// Round 8
// baseline (111.914 us; speedup 1.0000x reference)
//
#include <hip/hip_runtime.h>
#include <hip/hip_bf16.h>
#include <stdint.h>

typedef __attribute__((ext_vector_type(8))) short short8;
typedef __attribute__((ext_vector_type(4))) float float4_t;
typedef __attribute__((ext_vector_type(16))) float float16_t;

#define DDIM 128
#define SORTN 256
#define LROW 136     // LDS B row pitch in shorts (272 B): bank-clean for b128 reads
#define SCAP 1088    // per-token score capacity (floats); >= 2048 B for cand alias
#define NCHT 17      // selection chunks of 64 (covers n <= 1088)

__device__ inline unsigned short f32_to_bf16_rne(float f) {
    uint32_t u = __float_as_uint(f);
    return (unsigned short)((u + 0x7FFFu + ((u >> 16) & 1u)) >> 16);
}
__device__ inline float bf16_to_f32(unsigned short h) {
    return __uint_as_float(((uint32_t)h) << 16);
}
__device__ inline int ks_of(const int* seq_lens, int n_seq, int t) {
    int off = 0, r = 0;
    for (int i = 0; i < n_seq; ++i) {
        int nx = off + seq_lens[i];
        if (t < nx) { r = off; break; }
        off = nx;
    }
    return r;
}

// ---- pass 1: rotate k rows ----
__global__ __launch_bounds__(256) void rotate_k_kernel(
        const unsigned short* __restrict__ k, unsigned short* __restrict__ kr, int T) {
    int row = blockIdx.x * 16 + (threadIdx.x >> 4);
    if (row >= T) return;
    int l16 = threadIdx.x & 15;
    short8 in = *(const short8*)(k + (size_t)row * DDIM + 8 * l16);
    float f[8];
    #pragma unroll
    for (int j = 0; j < 8; ++j) f[j] = bf16_to_f32((unsigned short)in[j]);
    #pragma unroll
    for (int b = 1; b <= 4; b <<= 1)
        #pragma unroll
        for (int j = 0; j < 8; ++j)
            if (!(j & b)) { float a = f[j], c = f[j | b]; f[j] = a + c; f[j | b] = a - c; }
    #pragma unroll
    for (int m = 1; m <= 8; m <<= 1) {
        bool hi = (l16 & m) != 0;
        #pragma unroll
        for (int j = 0; j < 8; ++j) {
            float o = __shfl_xor(f[j], m, 64);
            f[j] = hi ? (o - f[j]) : (f[j] + o);
        }
    }
    const float sc = 0.08838834764831845f;
    short8 out;
    #pragma unroll
    for (int j = 0; j < 8; ++j) out[j] = (short)f32_to_bf16_rne(f[j] * sc);
    *(short8*)(kr + (size_t)row * DDIM + 8 * l16) = out;
}

// ---- pass 2: fused score + select ----
// R3 structure (session best, 100.28 us): 4 tokens / 4 waves, every wave holds
// all 4 tokens' A-fragments, owns 32 distinct rows of a 128-row LDS chunk
// (each staged row ds_read exactly once), register-prefetch staging with a
// full-chunk prefetch distance. R4-R7 alternatives (global_load_lds, direct
// register loads, permuted coalesced loads) all measured neutral-to-worse.
// This round's single variable: __launch_bounds__(256,3) -> cap VGPR ~168 so
// THREE blocks co-reside per CU (LDS 3*52224 <= 160K), adding a third
// independent wave per SIMD to hide barrier/lockstep bubbles.
// Selection: ballot+popcount binary search (verified R5-R7).
__global__ __launch_bounds__(256, 3) void fused_kernel(
        const unsigned short* __restrict__ q,   // [T,H,128] bf16 bits (unrotated)
        const unsigned short* __restrict__ kr,  // [T,128] rotated bf16 bits
        const float* __restrict__ w,            // [T,H]
        const int* __restrict__ seq_lens, int n_seq,
        float* __restrict__ out_vals, float* __restrict__ out_idx,
        int T, int H, int K, int Tt) {
    __shared__ __align__(16) unsigned short bL[128 * LROW];    // 34816 B
    __shared__ __align__(16) float scw[4][SCAP];               // 17408 B
    // rotated-q staging aliases scw (dead until first score write)
    unsigned short* qst = (unsigned short*)&scw[0][0];

    const int tid  = threadIdx.x;
    const int wv   = tid >> 6, lane = tid & 63;
    const int col  = lane & 15, kgrp = lane >> 4;
    const int hi   = lane >> 5;
    const int l31  = lane & 31;
    const int srow = tid >> 4, sseg = tid & 15;   // srow 0..15

    // makespan-balanced mapping for co-resident pair (m, m+Tt/2)
    const int m     = blockIdx.x;
    const int halfG = Tt >> 1;
    const int ttile = (Tt <= 1) ? 0 : ((m < halfG) ? m : (Tt - 1 - (m - halfG)));
    const int tt0   = ttile * 4;

    // per-token bounds (tokens tt0..tt0+3)
    const int tg1 = tt0 + 1, tg2 = tt0 + 2, tg3 = tt0 + 3;
    const bool v0 = (tt0 < T), v1 = (tg1 < T), v2 = (tg2 < T), v3 = (tg3 < T);
    const int t0 = v0 ? tt0 : T - 1, t1 = v1 ? tg1 : T - 1;
    const int t2 = v2 ? tg2 : T - 1, t3 = v3 ? tg3 : T - 1;
    const int ks0 = ks_of(seq_lens, n_seq, t0);
    const int ks1 = ks_of(seq_lens, n_seq, t1);
    const int ks2 = ks_of(seq_lens, n_seq, t2);
    const int ks3 = ks_of(seq_lens, n_seq, t3);

    const int bks    = ks_of(seq_lens, n_seq, tt0);
    const int bke    = (tt0 + 4 < T) ? (tt0 + 4) : T;
    const int nchunk = (bke - bks + 127) >> 7;

    // ---- prefetch chunk 0 (rows srow + 16*i, i=0..7) ----
    short8 pre[8];
    #pragma unroll
    for (int i = 0; i < 8; ++i) {
        int gs = bks + srow + 16 * i; if (gs > T - 1) gs = T - 1;
        pre[i] = *(const short8*)(kr + (size_t)gs * DDIM + sseg * 8);
    }

    // ---- rotate q[tt0+wv] in registers (16 head-rows; verified FWHT) ----
    const int t_r = (tt0 + wv < T) ? (tt0 + wv) : (T - 1);
    float f[4][8];
    const unsigned short* qrow = q + ((size_t)t_r * H + col) * DDIM + kgrp * 8;
    #pragma unroll
    for (int kk = 0; kk < 4; ++kk) {
        short8 v = *(const short8*)(qrow + kk * 32);
        #pragma unroll
        for (int j = 0; j < 8; ++j) f[kk][j] = bf16_to_f32((unsigned short)v[j]);
    }
    #pragma unroll
    for (int b = 1; b <= 4; b <<= 1)
        #pragma unroll
        for (int kk = 0; kk < 4; ++kk)
            #pragma unroll
            for (int j = 0; j < 8; ++j)
                if (!(j & b)) { float a = f[kk][j], c = f[kk][j | b];
                                f[kk][j] = a + c; f[kk][j | b] = a - c; }
    #pragma unroll
    for (int kk = 0; kk < 4; ++kk)
        #pragma unroll
        for (int j = 0; j < 8; ++j) {
            float o = __shfl_xor(f[kk][j], 16, 64);
            f[kk][j] = (kgrp & 1) ? (o - f[kk][j]) : (f[kk][j] + o);
        }
    #pragma unroll
    for (int kk = 0; kk < 4; ++kk)
        #pragma unroll
        for (int j = 0; j < 8; ++j) {
            float o = __shfl_xor(f[kk][j], 32, 64);
            f[kk][j] = (kgrp & 2) ? (o - f[kk][j]) : (f[kk][j] + o);
        }
    #pragma unroll
    for (int j = 0; j < 8; ++j) {
        { float a = f[0][j], c = f[1][j]; f[0][j] = a + c; f[1][j] = a - c; }
        { float a = f[2][j], c = f[3][j]; f[2][j] = a + c; f[3][j] = a - c; }
        { float a = f[0][j], c = f[2][j]; f[0][j] = a + c; f[2][j] = a - c; }
        { float a = f[1][j], c = f[3][j]; f[1][j] = a + c; f[3][j] = a - c; }
    }
    // store rotated q bf16 to qst[(wv*16+col)*136 + d], d = kgrp*8 + kk*32 + j
    const float scl = 0.08838834764831845f;
    #pragma unroll
    for (int kk = 0; kk < 4; ++kk) {
        short8 o;
        #pragma unroll
        for (int j = 0; j < 8; ++j) o[j] = (short)f32_to_bf16_rne(f[kk][j] * scl);
        *(short8*)&qst[(wv * 16 + col) * LROW + kgrp * 8 + kk * 32] = o;
    }
    __syncthreads();   // qst ready

    // ---- A fragments, BOTH pairs, in 32x32x16 layout: m = l31 (tok*16+head),
    //      k = hi*8 + j, kstep k8 covers d = 16*k8 + k ----
    short8 afrag0[8], afrag1[8];
    {
        const unsigned short* qr0 = qst + l31 * LROW + hi * 8;          // tok 0,1
        const unsigned short* qr1 = qst + (32 + l31) * LROW + hi * 8;   // tok 2,3
        #pragma unroll
        for (int k8 = 0; k8 < 8; ++k8) {
            afrag0[k8] = *(const short8*)(qr0 + 16 * k8);
            afrag1[k8] = *(const short8*)(qr1 + 16 * k8);
        }
    }
    // weights matched to C/D row layout: head = (r&3) + 8*((r>>2)&1) + 4*hi
    float w0r[8], w1r[8], w2r[8], w3r[8];
    #pragma unroll
    for (int r = 0; r < 8; ++r) {
        int h = (r & 3) + 8 * ((r >> 2) & 1) + 4 * hi;
        w0r[r] = w[(size_t)t0 * H + h];
        w1r[r] = w[(size_t)t1 * H + h];
        w2r[r] = w[(size_t)t2 * H + h];
        w3r[r] = w[(size_t)t3 * H + h];
    }
    __syncthreads();   // all waves done reading qst; scw may be overwritten

    // ---- score loop: 128-row chunks, single buffer, each row read once ----
    const int nrow = wv * 32 + l31;   // this wave's B row in the chunk
    for (int c = 0; c < nchunk; ++c) {
        const int kv0 = bks + (c << 7);
        // stage current chunk (pre regs -> LDS)
        #pragma unroll
        for (int i = 0; i < 8; ++i)
            *(short8*)&bL[(srow + 16 * i) * LROW + sseg * 8] = pre[i];
        __syncthreads();
        if (c + 1 < nchunk) {                  // issue next chunk's loads early
            int kvn = kv0 + 128;
            #pragma unroll
            for (int i = 0; i < 8; ++i) {
                int gs = kvn + srow + 16 * i; if (gs > T - 1) gs = T - 1;
                pre[i] = *(const short8*)(kr + (size_t)gs * DDIM + sseg * 8);
            }
        }
        const unsigned short* brow = &bL[nrow * LROW + hi * 8];
        float16_t acc01 = {0.f, 0.f, 0.f, 0.f, 0.f, 0.f, 0.f, 0.f,
                           0.f, 0.f, 0.f, 0.f, 0.f, 0.f, 0.f, 0.f};
        float16_t acc23 = {0.f, 0.f, 0.f, 0.f, 0.f, 0.f, 0.f, 0.f,
                           0.f, 0.f, 0.f, 0.f, 0.f, 0.f, 0.f, 0.f};
        __builtin_amdgcn_s_setprio(1);
        #pragma unroll
        for (int k8 = 0; k8 < 8; ++k8) {
            short8 bf = *(const short8*)(brow + 16 * k8);
            acc01 = __builtin_amdgcn_mfma_f32_32x32x16_bf16(afrag0[k8], bf, acc01, 0, 0, 0);
            acc23 = __builtin_amdgcn_mfma_f32_32x32x16_bf16(afrag1[k8], bf, acc23, 0, 0, 0);
        }
        __builtin_amdgcn_s_setprio(0);
        // weighted relu reduce over heads; lane + lane^32 hold the 16 heads
        float p0 = 0.f, p1 = 0.f, p2 = 0.f, p3 = 0.f;
        #pragma unroll
        for (int r = 0; r < 8; ++r) {
            float a = acc01[r];     a = a > 0.f ? a : 0.f; p0 += w0r[r] * a;
            float b = acc01[r + 8]; b = b > 0.f ? b : 0.f; p1 += w1r[r] * b;
            float g = acc23[r];     g = g > 0.f ? g : 0.f; p2 += w2r[r] * g;
            float d = acc23[r + 8]; d = d > 0.f ? d : 0.f; p3 += w3r[r] * d;
        }
        p0 += __shfl_xor(p0, 32, 64);
        p1 += __shfl_xor(p1, 32, 64);
        p2 += __shfl_xor(p2, 32, 64);
        p3 += __shfl_xor(p3, 32, 64);
        const int s = kv0 + nrow;
        if (hi == 0) {
            if (v0 && s >= ks0 && s <= t0) scw[0][s - ks0] = p0;
            if (v2 && s >= ks2 && s <= t2) scw[2][s - ks2] = p2;
        } else {
            if (v1 && s >= ks1 && s <= t1) scw[1][s - ks1] = p1;
            if (v3 && s >= ks3 && s <= t3) scw[3][s - ks3] = p3;
        }
        __syncthreads();
    }

    // ---- select: wave wv owns token tt0+wv ----
    const int t_s = tt0 + wv;
    if (t_s >= T) return;
    const int ks_w = ks_of(seq_lens, n_seq, t_s);
    const int ke_w = t_s + 1;
    const int n    = ke_w - ks_w;

    const int nch = (n + 63) >> 6;
    uint32_t ukey[NCHT];
    #pragma unroll
    for (int c = 0; c < NCHT; ++c) {
        if (c < nch) {
            int i = c * 64 + lane;
            ukey[c] = (i < n) ? __float_as_uint(scw[wv][i]) : 0u;
        } else ukey[c] = 0u;
    }
    unsigned long long* candw = (unsigned long long*)&scw[wv][0];

    const int Keff = (n < K) ? n : K;
    uint32_t ustar = 0;
    int ttake = K;
    if (n > K) {
        uint32_t lo = 0, hia = 0x80000000u;
        for (int it = 0; it < 31; ++it) {
            uint32_t mid = (lo + hia) >> 1;
            int total = 0;
            #pragma unroll
            for (int c = 0; c < NCHT; ++c)
                if (c < nch) total += (int)__popcll(__ballot(ukey[c] >= mid));
            if (total >= K) lo = mid; else hia = mid;
        }
        ustar = lo;
        int tg = 0;
        #pragma unroll
        for (int c = 0; c < NCHT; ++c)
            if (c < nch) tg += (int)__popcll(__ballot(ukey[c] > ustar));
        ttake = K - tg;
    }

    // gather exactly Keff keys (ties by ascending index)
    {
        const unsigned long long ltm = (1ull << lane) - 1ull;
        int base = 0, tieBase = 0;
        const bool selAll = (n <= K);
        #pragma unroll
        for (int c = 0; c < NCHT; ++c) {
            if (c < nch) {
                int i = c * 64 + lane;
                bool inb = (i < n);
                uint32_t u = ukey[c];
                bool isGt  = inb && (selAll || u > ustar);
                bool isTie = inb && !selAll && (u == ustar);
                unsigned long long mt = __ballot(isTie);
                int tr = tieBase + (int)__popcll(mt & ltm);
                bool take = isGt || (isTie && tr < ttake);
                unsigned long long mk = __ballot(take);
                if (take) {
                    int pos = base + (int)__popcll(mk & ltm);
                    int s = ks_w + i;
                    if (pos < SORTN)
                        candw[pos] = ((((unsigned long long)u << 11) |
                                       (unsigned long long)(T - 1 - s)) + 1ull);
                }
                base    += (int)__popcll(mk);
                tieBase += (int)__popcll(mt);
            }
        }
        for (int i = Keff + lane; i < SORTN; i += 64) candw[i] = 0ull;
    }

    // register bitonic sort of 256 keys, descending; e = 4*lane + r
    unsigned long long kreg[4];
    #pragma unroll
    for (int r = 0; r < 4; ++r) kreg[r] = candw[4 * lane + r];

    #define CX(a, b, dsc) { unsigned long long _mx = (a) > (b) ? (a) : (b); \
                            unsigned long long _mn = (a) > (b) ? (b) : (a); \
                            (a) = (dsc) ? _mx : _mn; (b) = (dsc) ? _mn : _mx; }
    #pragma unroll
    for (int size = 2; size <= SORTN; size <<= 1) {
        #pragma unroll
        for (int stride = SORTN >> 1; stride >= 4; stride >>= 1) {
            if (stride > (size >> 1)) continue;
            int lmask = stride >> 2;
            #pragma unroll
            for (int r = 0; r < 4; ++r) {
                int e = 4 * lane + r;
                unsigned long long other = __shfl_xor(kreg[r], lmask, 64);
                bool desc = ((e & size) == 0);
                bool iAmLow = ((e & stride) == 0);
                bool keepMax = (iAmLow == desc);
                kreg[r] = keepMax ? (kreg[r] > other ? kreg[r] : other)
                                  : (kreg[r] < other ? kreg[r] : other);
            }
        }
        if (size >= 4) {
            bool d = (((4 * lane) & size) == 0);
            CX(kreg[0], kreg[2], d);
            CX(kreg[1], kreg[3], d);
            CX(kreg[0], kreg[1], d);
            CX(kreg[2], kreg[3], d);
        } else {
            CX(kreg[0], kreg[1], true);
            CX(kreg[2], kreg[3], false);
        }
    }
    #undef CX

    // ---- emit ----
    if (4 * lane < K) {
        float4_t v4, i4;
        #pragma unroll
        for (int r = 0; r < 4; ++r) {
            int e = 4 * lane + r;
            unsigned long long key = kreg[r];
            float v; int idx;
            if (key != 0ull) {
                unsigned long long km1 = key - 1ull;
                v = __uint_as_float((uint32_t)(km1 >> 11));
                idx = T - 1 - (int)(km1 & 0x7FFull);
            } else {
                int pidx = e - Keff;
                idx = (pidx < ks_w) ? pidx : (ke_w + (pidx - ks_w));
                v = -1e30f;
            }
            v4[r] = v; i4[r] = (float)idx;
        }
        *(float4_t*)(out_vals + (size_t)t_s * K + 4 * lane) = v4;
        *(float4_t*)(out_idx  + (size_t)t_s * K + 4 * lane) = i4;
    }
}

extern "C" void kernel_launch(void* const* d_in, const int* in_sizes, int n_in,
                              void* d_out, int out_size, void* d_ws, size_t ws_size,
                              hipStream_t stream) {
    const unsigned short* q = (const unsigned short*)d_in[0];
    const unsigned short* k = (const unsigned short*)d_in[1];
    const float* w          = (const float*)d_in[2];
    const int* seq_lens     = (const int*)d_in[3];
    const int n_seq = in_sizes[3];
    const int T = in_sizes[1] / DDIM;
    const int H = in_sizes[2] / T;
    const int K = out_size / (2 * T);

    unsigned short* kr = (unsigned short*)d_ws;   // [T,128] rotated k (512 KB)
    float* out_vals = (float*)d_out;
    float* out_idx  = out_vals + (size_t)T * K;

    rotate_k_kernel<<<dim3((T + 15) / 16), dim3(256), 0, stream>>>(k, kr, T);
    const int Tt = (T + 3) / 4;
    fused_kernel<<<dim3(Tt), dim3(256), 0, stream>>>(
        q, kr, w, seq_lens, n_seq, out_vals, out_idx, T, H, K, Tt);
}

// Round 10
// 104.985 us; speedup vs baseline: 1.0660x; 1.0660x over previous
//
#include <hip/hip_runtime.h>
#include <hip/hip_bf16.h>
#include <stdint.h>

typedef __attribute__((ext_vector_type(8))) short short8;
typedef __attribute__((ext_vector_type(4))) float float4_t;
typedef __attribute__((ext_vector_type(16))) float float16_t;

#define DDIM 128
#define SORTN 256
#define LROW 136     // LDS B row pitch in shorts (272 B): bank-clean for b128 reads
#define SCAP 1088    // per-token score capacity (floats); >= 2048 B for cand alias
#define NCHT 17      // selection chunks of 64 (covers n <= 1088)

__device__ inline unsigned short f32_to_bf16_rne(float f) {
    uint32_t u = __float_as_uint(f);
    return (unsigned short)((u + 0x7FFFu + ((u >> 16) & 1u)) >> 16);
}
__device__ inline float bf16_to_f32(unsigned short h) {
    return __uint_as_float(((uint32_t)h) << 16);
}
__device__ inline int ks_of(const int* seq_lens, int n_seq, int t) {
    int off = 0, r = 0;
    for (int i = 0; i < n_seq; ++i) {
        int nx = off + seq_lens[i];
        if (t < nx) { r = off; break; }
        off = nx;
    }
    return r;
}

// ---- pass 1: rotate k rows ----
__global__ __launch_bounds__(256) void rotate_k_kernel(
        const unsigned short* __restrict__ k, unsigned short* __restrict__ kr, int T) {
    int row = blockIdx.x * 16 + (threadIdx.x >> 4);
    if (row >= T) return;
    int l16 = threadIdx.x & 15;
    short8 in = *(const short8*)(k + (size_t)row * DDIM + 8 * l16);
    float f[8];
    #pragma unroll
    for (int j = 0; j < 8; ++j) f[j] = bf16_to_f32((unsigned short)in[j]);
    #pragma unroll
    for (int b = 1; b <= 4; b <<= 1)
        #pragma unroll
        for (int j = 0; j < 8; ++j)
            if (!(j & b)) { float a = f[j], c = f[j | b]; f[j] = a + c; f[j | b] = a - c; }
    #pragma unroll
    for (int m = 1; m <= 8; m <<= 1) {
        bool hi = (l16 & m) != 0;
        #pragma unroll
        for (int j = 0; j < 8; ++j) {
            float o = __shfl_xor(f[j], m, 64);
            f[j] = hi ? (o - f[j]) : (f[j] + o);
        }
    }
    const float sc = 0.08838834764831845f;
    short8 out;
    #pragma unroll
    for (int j = 0; j < 8; ++j) out[j] = (short)f32_to_bf16_rne(f[j] * sc);
    *(short8*)(kr + (size_t)row * DDIM + 8 * l16) = out;
}

// ---- pass 2: fused score + select ----
// Measured-optimal structure (R3, 100.28 us): 4 tokens / 4 waves, every wave
// holds all 4 tokens' A-fragments, owns 32 distinct rows of a 128-row LDS
// chunk (each staged row ds_read exactly once), register-prefetch staging with
// full-chunk prefetch distance, 2 barriers/chunk. Alternatives all measured
// worse: gll single-buffer (R4, exposed vmcnt drain), barrier-free direct
// loads (R6), coalesced permuted direct loads (R7), launch_bounds(256,3)
// (R8: VGPR squeezed to 84 -> scratch spills, fused 47 us).
// Selection: ballot+popcount binary search (SALU counting; verified R5-R7).
__global__ __launch_bounds__(256, 2) void fused_kernel(
        const unsigned short* __restrict__ q,   // [T,H,128] bf16 bits (unrotated)
        const unsigned short* __restrict__ kr,  // [T,128] rotated bf16 bits
        const float* __restrict__ w,            // [T,H]
        const int* __restrict__ seq_lens, int n_seq,
        float* __restrict__ out_vals, float* __restrict__ out_idx,
        int T, int H, int K, int Tt) {
    __shared__ __align__(16) unsigned short bL[128 * LROW];    // 34816 B
    __shared__ __align__(16) float scw[4][SCAP];               // 17408 B
    // rotated-q staging aliases scw (dead until first score write)
    unsigned short* qst = (unsigned short*)&scw[0][0];

    const int tid  = threadIdx.x;
    const int wv   = tid >> 6, lane = tid & 63;
    const int col  = lane & 15, kgrp = lane >> 4;
    const int hi   = lane >> 5;
    const int l31  = lane & 31;
    const int srow = tid >> 4, sseg = tid & 15;   // srow 0..15

    // makespan-balanced mapping for co-resident pair (m, m+Tt/2)
    const int m     = blockIdx.x;
    const int halfG = Tt >> 1;
    const int ttile = (Tt <= 1) ? 0 : ((m < halfG) ? m : (Tt - 1 - (m - halfG)));
    const int tt0   = ttile * 4;

    // per-token bounds (tokens tt0..tt0+3)
    const int tg1 = tt0 + 1, tg2 = tt0 + 2, tg3 = tt0 + 3;
    const bool v0 = (tt0 < T), v1 = (tg1 < T), v2 = (tg2 < T), v3 = (tg3 < T);
    const int t0 = v0 ? tt0 : T - 1, t1 = v1 ? tg1 : T - 1;
    const int t2 = v2 ? tg2 : T - 1, t3 = v3 ? tg3 : T - 1;
    const int ks0 = ks_of(seq_lens, n_seq, t0);
    const int ks1 = ks_of(seq_lens, n_seq, t1);
    const int ks2 = ks_of(seq_lens, n_seq, t2);
    const int ks3 = ks_of(seq_lens, n_seq, t3);

    const int bks    = ks_of(seq_lens, n_seq, tt0);
    const int bke    = (tt0 + 4 < T) ? (tt0 + 4) : T;
    const int nchunk = (bke - bks + 127) >> 7;

    // ---- prefetch chunk 0 (rows srow + 16*i, i=0..7) ----
    short8 pre[8];
    #pragma unroll
    for (int i = 0; i < 8; ++i) {
        int gs = bks + srow + 16 * i; if (gs > T - 1) gs = T - 1;
        pre[i] = *(const short8*)(kr + (size_t)gs * DDIM + sseg * 8);
    }

    // ---- rotate q[tt0+wv] in registers (16 head-rows; verified FWHT) ----
    const int t_r = (tt0 + wv < T) ? (tt0 + wv) : (T - 1);
    float f[4][8];
    const unsigned short* qrow = q + ((size_t)t_r * H + col) * DDIM + kgrp * 8;
    #pragma unroll
    for (int kk = 0; kk < 4; ++kk) {
        short8 v = *(const short8*)(qrow + kk * 32);
        #pragma unroll
        for (int j = 0; j < 8; ++j) f[kk][j] = bf16_to_f32((unsigned short)v[j]);
    }
    #pragma unroll
    for (int b = 1; b <= 4; b <<= 1)
        #pragma unroll
        for (int kk = 0; kk < 4; ++kk)
            #pragma unroll
            for (int j = 0; j < 8; ++j)
                if (!(j & b)) { float a = f[kk][j], c = f[kk][j | b];
                                f[kk][j] = a + c; f[kk][j | b] = a - c; }
    #pragma unroll
    for (int kk = 0; kk < 4; ++kk)
        #pragma unroll
        for (int j = 0; j < 8; ++j) {
            float o = __shfl_xor(f[kk][j], 16, 64);
            f[kk][j] = (kgrp & 1) ? (o - f[kk][j]) : (f[kk][j] + o);
        }
    #pragma unroll
    for (int kk = 0; kk < 4; ++kk)
        #pragma unroll
        for (int j = 0; j < 8; ++j) {
            float o = __shfl_xor(f[kk][j], 32, 64);
            f[kk][j] = (kgrp & 2) ? (o - f[kk][j]) : (f[kk][j] + o);
        }
    #pragma unroll
    for (int j = 0; j < 8; ++j) {
        { float a = f[0][j], c = f[1][j]; f[0][j] = a + c; f[1][j] = a - c; }
        { float a = f[2][j], c = f[3][j]; f[2][j] = a + c; f[3][j] = a - c; }
        { float a = f[0][j], c = f[2][j]; f[0][j] = a + c; f[2][j] = a - c; }
        { float a = f[1][j], c = f[3][j]; f[1][j] = a + c; f[3][j] = a - c; }
    }
    // store rotated q bf16 to qst[(wv*16+col)*136 + d], d = kgrp*8 + kk*32 + j
    const float scl = 0.08838834764831845f;
    #pragma unroll
    for (int kk = 0; kk < 4; ++kk) {
        short8 o;
        #pragma unroll
        for (int j = 0; j < 8; ++j) o[j] = (short)f32_to_bf16_rne(f[kk][j] * scl);
        *(short8*)&qst[(wv * 16 + col) * LROW + kgrp * 8 + kk * 32] = o;
    }
    __syncthreads();   // qst ready

    // ---- A fragments, BOTH pairs, in 32x32x16 layout: m = l31 (tok*16+head),
    //      k = hi*8 + j, kstep k8 covers d = 16*k8 + k ----
    short8 afrag0[8], afrag1[8];
    {
        const unsigned short* qr0 = qst + l31 * LROW + hi * 8;          // tok 0,1
        const unsigned short* qr1 = qst + (32 + l31) * LROW + hi * 8;   // tok 2,3
        #pragma unroll
        for (int k8 = 0; k8 < 8; ++k8) {
            afrag0[k8] = *(const short8*)(qr0 + 16 * k8);
            afrag1[k8] = *(const short8*)(qr1 + 16 * k8);
        }
    }
    // weights matched to C/D row layout: head = (r&3) + 8*((r>>2)&1) + 4*hi
    float w0r[8], w1r[8], w2r[8], w3r[8];
    #pragma unroll
    for (int r = 0; r < 8; ++r) {
        int h = (r & 3) + 8 * ((r >> 2) & 1) + 4 * hi;
        w0r[r] = w[(size_t)t0 * H + h];
        w1r[r] = w[(size_t)t1 * H + h];
        w2r[r] = w[(size_t)t2 * H + h];
        w3r[r] = w[(size_t)t3 * H + h];
    }
    __syncthreads();   // all waves done reading qst; scw may be overwritten

    // ---- score loop: 128-row chunks, single buffer, each row read once ----
    const int nrow = wv * 32 + l31;   // this wave's B row in the chunk
    for (int c = 0; c < nchunk; ++c) {
        const int kv0 = bks + (c << 7);
        // stage current chunk (pre regs -> LDS)
        #pragma unroll
        for (int i = 0; i < 8; ++i)
            *(short8*)&bL[(srow + 16 * i) * LROW + sseg * 8] = pre[i];
        __syncthreads();
        if (c + 1 < nchunk) {                  // issue next chunk's loads early
            int kvn = kv0 + 128;
            #pragma unroll
            for (int i = 0; i < 8; ++i) {
                int gs = kvn + srow + 16 * i; if (gs > T - 1) gs = T - 1;
                pre[i] = *(const short8*)(kr + (size_t)gs * DDIM + sseg * 8);
            }
        }
        const unsigned short* brow = &bL[nrow * LROW + hi * 8];
        float16_t acc01 = {0.f, 0.f, 0.f, 0.f, 0.f, 0.f, 0.f, 0.f,
                           0.f, 0.f, 0.f, 0.f, 0.f, 0.f, 0.f, 0.f};
        float16_t acc23 = {0.f, 0.f, 0.f, 0.f, 0.f, 0.f, 0.f, 0.f,
                           0.f, 0.f, 0.f, 0.f, 0.f, 0.f, 0.f, 0.f};
        __builtin_amdgcn_s_setprio(1);
        #pragma unroll
        for (int k8 = 0; k8 < 8; ++k8) {
            short8 bf = *(const short8*)(brow + 16 * k8);
            acc01 = __builtin_amdgcn_mfma_f32_32x32x16_bf16(afrag0[k8], bf, acc01, 0, 0, 0);
            acc23 = __builtin_amdgcn_mfma_f32_32x32x16_bf16(afrag1[k8], bf, acc23, 0, 0, 0);
        }
        __builtin_amdgcn_s_setprio(0);
        // weighted relu reduce over heads; lane + lane^32 hold the 16 heads
        float p0 = 0.f, p1 = 0.f, p2 = 0.f, p3 = 0.f;
        #pragma unroll
        for (int r = 0; r < 8; ++r) {
            float a = acc01[r];     a = a > 0.f ? a : 0.f; p0 += w0r[r] * a;
            float b = acc01[r + 8]; b = b > 0.f ? b : 0.f; p1 += w1r[r] * b;
            float g = acc23[r];     g = g > 0.f ? g : 0.f; p2 += w2r[r] * g;
            float d = acc23[r + 8]; d = d > 0.f ? d : 0.f; p3 += w3r[r] * d;
        }
        p0 += __shfl_xor(p0, 32, 64);
        p1 += __shfl_xor(p1, 32, 64);
        p2 += __shfl_xor(p2, 32, 64);
        p3 += __shfl_xor(p3, 32, 64);
        const int s = kv0 + nrow;
        if (hi == 0) {
            if (v0 && s >= ks0 && s <= t0) scw[0][s - ks0] = p0;
            if (v2 && s >= ks2 && s <= t2) scw[2][s - ks2] = p2;
        } else {
            if (v1 && s >= ks1 && s <= t1) scw[1][s - ks1] = p1;
            if (v3 && s >= ks3 && s <= t3) scw[3][s - ks3] = p3;
        }
        __syncthreads();
    }

    // ---- select: wave wv owns token tt0+wv ----
    const int t_s = tt0 + wv;
    if (t_s >= T) return;
    const int ks_w = ks_of(seq_lens, n_seq, t_s);
    const int ke_w = t_s + 1;
    const int n    = ke_w - ks_w;

    const int nch = (n + 63) >> 6;
    uint32_t ukey[NCHT];
    #pragma unroll
    for (int c = 0; c < NCHT; ++c) {
        if (c < nch) {
            int i = c * 64 + lane;
            ukey[c] = (i < n) ? __float_as_uint(scw[wv][i]) : 0u;
        } else ukey[c] = 0u;
    }
    unsigned long long* candw = (unsigned long long*)&scw[wv][0];

    const int Keff = (n < K) ? n : K;
    uint32_t ustar = 0;
    int ttake = K;
    if (n > K) {
        uint32_t lo = 0, hia = 0x80000000u;
        for (int it = 0; it < 31; ++it) {
            uint32_t mid = (lo + hia) >> 1;
            int total = 0;
            #pragma unroll
            for (int c = 0; c < NCHT; ++c)
                if (c < nch) total += (int)__popcll(__ballot(ukey[c] >= mid));
            if (total >= K) lo = mid; else hia = mid;
        }
        ustar = lo;
        int tg = 0;
        #pragma unroll
        for (int c = 0; c < NCHT; ++c)
            if (c < nch) tg += (int)__popcll(__ballot(ukey[c] > ustar));
        ttake = K - tg;
    }

    // gather exactly Keff keys (ties by ascending index)
    {
        const unsigned long long ltm = (1ull << lane) - 1ull;
        int base = 0, tieBase = 0;
        const bool selAll = (n <= K);
        #pragma unroll
        for (int c = 0; c < NCHT; ++c) {
            if (c < nch) {
                int i = c * 64 + lane;
                bool inb = (i < n);
                uint32_t u = ukey[c];
                bool isGt  = inb && (selAll || u > ustar);
                bool isTie = inb && !selAll && (u == ustar);
                unsigned long long mt = __ballot(isTie);
                int tr = tieBase + (int)__popcll(mt & ltm);
                bool take = isGt || (isTie && tr < ttake);
                unsigned long long mk = __ballot(take);
                if (take) {
                    int pos = base + (int)__popcll(mk & ltm);
                    int s = ks_w + i;
                    if (pos < SORTN)
                        candw[pos] = ((((unsigned long long)u << 11) |
                                       (unsigned long long)(T - 1 - s)) + 1ull);
                }
                base    += (int)__popcll(mk);
                tieBase += (int)__popcll(mt);
            }
        }
        for (int i = Keff + lane; i < SORTN; i += 64) candw[i] = 0ull;
    }

    // register bitonic sort of 256 keys, descending; e = 4*lane + r
    unsigned long long kreg[4];
    #pragma unroll
    for (int r = 0; r < 4; ++r) kreg[r] = candw[4 * lane + r];

    #define CX(a, b, dsc) { unsigned long long _mx = (a) > (b) ? (a) : (b); \
                            unsigned long long _mn = (a) > (b) ? (b) : (a); \
                            (a) = (dsc) ? _mx : _mn; (b) = (dsc) ? _mn : _mx; }
    #pragma unroll
    for (int size = 2; size <= SORTN; size <<= 1) {
        #pragma unroll
        for (int stride = SORTN >> 1; stride >= 4; stride >>= 1) {
            if (stride > (size >> 1)) continue;
            int lmask = stride >> 2;
            #pragma unroll
            for (int r = 0; r < 4; ++r) {
                int e = 4 * lane + r;
                unsigned long long other = __shfl_xor(kreg[r], lmask, 64);
                bool desc = ((e & size) == 0);
                bool iAmLow = ((e & stride) == 0);
                bool keepMax = (iAmLow == desc);
                kreg[r] = keepMax ? (kreg[r] > other ? kreg[r] : other)
                                  : (kreg[r] < other ? kreg[r] : other);
            }
        }
        if (size >= 4) {
            bool d = (((4 * lane) & size) == 0);
            CX(kreg[0], kreg[2], d);
            CX(kreg[1], kreg[3], d);
            CX(kreg[0], kreg[1], d);
            CX(kreg[2], kreg[3], d);
        } else {
            CX(kreg[0], kreg[1], true);
            CX(kreg[2], kreg[3], false);
        }
    }
    #undef CX

    // ---- emit ----
    if (4 * lane < K) {
        float4_t v4, i4;
        #pragma unroll
        for (int r = 0; r < 4; ++r) {
            int e = 4 * lane + r;
            unsigned long long key = kreg[r];
            float v; int idx;
            if (key != 0ull) {
                unsigned long long km1 = key - 1ull;
                v = __uint_as_float((uint32_t)(km1 >> 11));
                idx = T - 1 - (int)(km1 & 0x7FFull);
            } else {
                int pidx = e - Keff;
                idx = (pidx < ks_w) ? pidx : (ke_w + (pidx - ks_w));
                v = -1e30f;
            }
            v4[r] = v; i4[r] = (float)idx;
        }
        *(float4_t*)(out_vals + (size_t)t_s * K + 4 * lane) = v4;
        *(float4_t*)(out_idx  + (size_t)t_s * K + 4 * lane) = i4;
    }
}

extern "C" void kernel_launch(void* const* d_in, const int* in_sizes, int n_in,
                              void* d_out, int out_size, void* d_ws, size_t ws_size,
                              hipStream_t stream) {
    const unsigned short* q = (const unsigned short*)d_in[0];
    const unsigned short* k = (const unsigned short*)d_in[1];
    const float* w          = (const float*)d_in[2];
    const int* seq_lens     = (const int*)d_in[3];
    const int n_seq = in_sizes[3];
    const int T = in_sizes[1] / DDIM;
    const int H = in_sizes[2] / T;
    const int K = out_size / (2 * T);

    unsigned short* kr = (unsigned short*)d_ws;   // [T,128] rotated k (512 KB)
    float* out_vals = (float*)d_out;
    float* out_idx  = out_vals + (size_t)T * K;

    rotate_k_kernel<<<dim3((T + 15) / 16), dim3(256), 0, stream>>>(k, kr, T);
    const int Tt = (T + 3) / 4;
    fused_kernel<<<dim3(Tt), dim3(256), 0, stream>>>(
        q, kr, w, seq_lens, n_seq, out_vals, out_idx, T, H, K, Tt);
}

// Round 11
// 99.189 us; speedup vs baseline: 1.1283x; 1.0584x over previous
//
#include <hip/hip_runtime.h>
#include <hip/hip_bf16.h>
#include <stdint.h>

typedef __attribute__((ext_vector_type(8))) short short8;
typedef __attribute__((ext_vector_type(4))) float float4_t;
typedef __attribute__((ext_vector_type(16))) float float16_t;

#define DDIM 128
#define SORTN 256
#define LROW 136     // LDS B row pitch in shorts (272 B): bank-clean for b128 reads
#define SCAP 1088    // per-token score capacity (floats); >= 2048 B for cand alias
#define NCHT 17      // selection chunks of 64 (covers n <= 1088)

__device__ inline unsigned short f32_to_bf16_rne(float f) {
    uint32_t u = __float_as_uint(f);
    return (unsigned short)((u + 0x7FFFu + ((u >> 16) & 1u)) >> 16);
}
__device__ inline float bf16_to_f32(unsigned short h) {
    return __uint_as_float(((uint32_t)h) << 16);
}
__device__ inline int ks_of(const int* seq_lens, int n_seq, int t) {
    int off = 0, r = 0;
    for (int i = 0; i < n_seq; ++i) {
        int nx = off + seq_lens[i];
        if (t < nx) { r = off; break; }
        off = nx;
    }
    return r;
}

// wave64 sum via DPP (VALU pipe; per-lane accumulate + ONE cross-lane reduce).
// Measured 4.7 us faster than per-chunk ballot+popcount (R3=100.3 vs R5/R10~105):
// cross-lane syncs dominate selection cost, not op counts.
__device__ inline int wave_reduce_add_dpp(int x) {
    x += __builtin_amdgcn_update_dpp(0, x, 0x111, 0xF, 0xF, true); // row_shr:1
    x += __builtin_amdgcn_update_dpp(0, x, 0x112, 0xF, 0xF, true); // row_shr:2
    x += __builtin_amdgcn_update_dpp(0, x, 0x114, 0xF, 0xF, true); // row_shr:4
    x += __builtin_amdgcn_update_dpp(0, x, 0x118, 0xF, 0xF, true); // row_shr:8
    x += __builtin_amdgcn_update_dpp(0, x, 0x142, 0xA, 0xF, true); // row_bcast:15
    x += __builtin_amdgcn_update_dpp(0, x, 0x143, 0xC, 0xF, true); // row_bcast:31
    return __builtin_amdgcn_readlane(x, 63);
}

// ---- pass 1: rotate k rows ----
__global__ __launch_bounds__(256) void rotate_k_kernel(
        const unsigned short* __restrict__ k, unsigned short* __restrict__ kr, int T) {
    int row = blockIdx.x * 16 + (threadIdx.x >> 4);
    if (row >= T) return;
    int l16 = threadIdx.x & 15;
    short8 in = *(const short8*)(k + (size_t)row * DDIM + 8 * l16);
    float f[8];
    #pragma unroll
    for (int j = 0; j < 8; ++j) f[j] = bf16_to_f32((unsigned short)in[j]);
    #pragma unroll
    for (int b = 1; b <= 4; b <<= 1)
        #pragma unroll
        for (int j = 0; j < 8; ++j)
            if (!(j & b)) { float a = f[j], c = f[j | b]; f[j] = a + c; f[j | b] = a - c; }
    #pragma unroll
    for (int m = 1; m <= 8; m <<= 1) {
        bool hi = (l16 & m) != 0;
        #pragma unroll
        for (int j = 0; j < 8; ++j) {
            float o = __shfl_xor(f[j], m, 64);
            f[j] = hi ? (o - f[j]) : (f[j] + o);
        }
    }
    const float sc = 0.08838834764831845f;
    short8 out;
    #pragma unroll
    for (int j = 0; j < 8; ++j) out[j] = (short)f32_to_bf16_rne(f[j] * sc);
    *(short8*)(kr + (size_t)row * DDIM + 8 * l16) = out;
}

// ---- pass 2: fused score + select ----
// Measured-optimal configuration (R3, 100.28 us), reverted byte-identical.
// block = 4 tokens, 4 waves (256 thr). Every wave holds ALL 4 tokens' rotated-q
// A-fragments in registers (2x 32x32 A tiles) and owns 32 DISTINCT KV rows of a
// 128-row chunk: each staged row is ds_read exactly once per block (2 MFMA per
// B-fragment). Register-prefetch staging with full-chunk prefetch distance;
// 2 barriers/chunk. Rejected by measurement: gll single-buffer (R4 +5us),
// barrier-free direct loads (R6 +2.5), permuted coalesced loads (R7 +3.5),
// launch_bounds(256,3) (R8 +11, VGPR->84 spills), ballot selection (R5/R10 +4.7).
__global__ __launch_bounds__(256, 2) void fused_kernel(
        const unsigned short* __restrict__ q,   // [T,H,128] bf16 bits (unrotated)
        const unsigned short* __restrict__ kr,  // [T,128] rotated bf16 bits
        const float* __restrict__ w,            // [T,H]
        const int* __restrict__ seq_lens, int n_seq,
        float* __restrict__ out_vals, float* __restrict__ out_idx,
        int T, int H, int K, int Tt) {
    __shared__ __align__(16) unsigned short bL[128 * LROW];    // 34816 B
    __shared__ __align__(16) float scw[4][SCAP];               // 17408 B
    // rotated-q staging aliases scw (dead until first score write):
    // 64 rows (4 tok x 16 heads) x 136 shorts = 17408 B exactly.
    unsigned short* qst = (unsigned short*)&scw[0][0];

    const int tid  = threadIdx.x;
    const int wv   = tid >> 6, lane = tid & 63;
    const int col  = lane & 15, kgrp = lane >> 4;
    const int hi   = lane >> 5;
    const int l31  = lane & 31;
    const int srow = tid >> 4, sseg = tid & 15;   // srow 0..15

    // makespan-balanced mapping for co-resident pair (m, m+Tt/2)
    const int m     = blockIdx.x;
    const int halfG = Tt >> 1;
    const int ttile = (Tt <= 1) ? 0 : ((m < halfG) ? m : (Tt - 1 - (m - halfG)));
    const int tt0   = ttile * 4;

    // per-token bounds (tokens tt0..tt0+3); constant-indexed only (no scratch)
    const int tg1 = tt0 + 1, tg2 = tt0 + 2, tg3 = tt0 + 3;
    const bool v0 = (tt0 < T), v1 = (tg1 < T), v2 = (tg2 < T), v3 = (tg3 < T);
    const int t0 = v0 ? tt0 : T - 1, t1 = v1 ? tg1 : T - 1;
    const int t2 = v2 ? tg2 : T - 1, t3 = v3 ? tg3 : T - 1;
    const int ks0 = ks_of(seq_lens, n_seq, t0);
    const int ks1 = ks_of(seq_lens, n_seq, t1);
    const int ks2 = ks_of(seq_lens, n_seq, t2);
    const int ks3 = ks_of(seq_lens, n_seq, t3);

    const int bks    = ks_of(seq_lens, n_seq, tt0);
    const int bke    = (tt0 + 4 < T) ? (tt0 + 4) : T;
    const int nchunk = (bke - bks + 127) >> 7;

    // ---- prefetch chunk 0 (rows srow + 16*i, i=0..7) ----
    short8 pre[8];
    #pragma unroll
    for (int i = 0; i < 8; ++i) {
        int gs = bks + srow + 16 * i; if (gs > T - 1) gs = T - 1;
        pre[i] = *(const short8*)(kr + (size_t)gs * DDIM + sseg * 8);
    }

    // ---- rotate q[tt0+wv] in registers (16 head-rows; verified FWHT) ----
    const int t_r = (tt0 + wv < T) ? (tt0 + wv) : (T - 1);
    float f[4][8];
    const unsigned short* qrow = q + ((size_t)t_r * H + col) * DDIM + kgrp * 8;
    #pragma unroll
    for (int kk = 0; kk < 4; ++kk) {
        short8 v = *(const short8*)(qrow + kk * 32);
        #pragma unroll
        for (int j = 0; j < 8; ++j) f[kk][j] = bf16_to_f32((unsigned short)v[j]);
    }
    #pragma unroll
    for (int b = 1; b <= 4; b <<= 1)
        #pragma unroll
        for (int kk = 0; kk < 4; ++kk)
            #pragma unroll
            for (int j = 0; j < 8; ++j)
                if (!(j & b)) { float a = f[kk][j], c = f[kk][j | b];
                                f[kk][j] = a + c; f[kk][j | b] = a - c; }
    #pragma unroll
    for (int kk = 0; kk < 4; ++kk)
        #pragma unroll
        for (int j = 0; j < 8; ++j) {
            float o = __shfl_xor(f[kk][j], 16, 64);
            f[kk][j] = (kgrp & 1) ? (o - f[kk][j]) : (f[kk][j] + o);
        }
    #pragma unroll
    for (int kk = 0; kk < 4; ++kk)
        #pragma unroll
        for (int j = 0; j < 8; ++j) {
            float o = __shfl_xor(f[kk][j], 32, 64);
            f[kk][j] = (kgrp & 2) ? (o - f[kk][j]) : (f[kk][j] + o);
        }
    #pragma unroll
    for (int j = 0; j < 8; ++j) {
        { float a = f[0][j], c = f[1][j]; f[0][j] = a + c; f[1][j] = a - c; }
        { float a = f[2][j], c = f[3][j]; f[2][j] = a + c; f[3][j] = a - c; }
        { float a = f[0][j], c = f[2][j]; f[0][j] = a + c; f[2][j] = a - c; }
        { float a = f[1][j], c = f[3][j]; f[1][j] = a + c; f[3][j] = a - c; }
    }
    // store rotated q bf16 to qst[(wv*16+col)*136 + d], d = kgrp*8 + kk*32 + j
    const float scl = 0.08838834764831845f;
    #pragma unroll
    for (int kk = 0; kk < 4; ++kk) {
        short8 o;
        #pragma unroll
        for (int j = 0; j < 8; ++j) o[j] = (short)f32_to_bf16_rne(f[kk][j] * scl);
        *(short8*)&qst[(wv * 16 + col) * LROW + kgrp * 8 + kk * 32] = o;
    }
    __syncthreads();   // qst ready

    // ---- A fragments, BOTH pairs, in 32x32x16 layout: m = l31 (tok*16+head),
    //      k = hi*8 + j, kstep k8 covers d = 16*k8 + k ----
    short8 afrag0[8], afrag1[8];
    {
        const unsigned short* qr0 = qst + l31 * LROW + hi * 8;          // tok 0,1
        const unsigned short* qr1 = qst + (32 + l31) * LROW + hi * 8;   // tok 2,3
        #pragma unroll
        for (int k8 = 0; k8 < 8; ++k8) {
            afrag0[k8] = *(const short8*)(qr0 + 16 * k8);
            afrag1[k8] = *(const short8*)(qr1 + 16 * k8);
        }
    }
    // weights matched to C/D row layout: head = (r&3) + 8*((r>>2)&1) + 4*hi
    float w0r[8], w1r[8], w2r[8], w3r[8];
    #pragma unroll
    for (int r = 0; r < 8; ++r) {
        int h = (r & 3) + 8 * ((r >> 2) & 1) + 4 * hi;
        w0r[r] = w[(size_t)t0 * H + h];
        w1r[r] = w[(size_t)t1 * H + h];
        w2r[r] = w[(size_t)t2 * H + h];
        w3r[r] = w[(size_t)t3 * H + h];
    }
    __syncthreads();   // all waves done reading qst; scw may be overwritten

    // ---- score loop: 128-row chunks, single buffer, each row read once ----
    const int nrow = wv * 32 + l31;   // this wave's B row in the chunk
    for (int c = 0; c < nchunk; ++c) {
        const int kv0 = bks + (c << 7);
        // stage current chunk (pre regs -> LDS)
        #pragma unroll
        for (int i = 0; i < 8; ++i)
            *(short8*)&bL[(srow + 16 * i) * LROW + sseg * 8] = pre[i];
        __syncthreads();
        if (c + 1 < nchunk) {                  // issue next chunk's loads early
            int kvn = kv0 + 128;
            #pragma unroll
            for (int i = 0; i < 8; ++i) {
                int gs = kvn + srow + 16 * i; if (gs > T - 1) gs = T - 1;
                pre[i] = *(const short8*)(kr + (size_t)gs * DDIM + sseg * 8);
            }
        }
        const unsigned short* brow = &bL[nrow * LROW + hi * 8];
        float16_t acc01 = {0.f, 0.f, 0.f, 0.f, 0.f, 0.f, 0.f, 0.f,
                           0.f, 0.f, 0.f, 0.f, 0.f, 0.f, 0.f, 0.f};
        float16_t acc23 = {0.f, 0.f, 0.f, 0.f, 0.f, 0.f, 0.f, 0.f,
                           0.f, 0.f, 0.f, 0.f, 0.f, 0.f, 0.f, 0.f};
        __builtin_amdgcn_s_setprio(1);
        #pragma unroll
        for (int k8 = 0; k8 < 8; ++k8) {
            short8 bf = *(const short8*)(brow + 16 * k8);
            acc01 = __builtin_amdgcn_mfma_f32_32x32x16_bf16(afrag0[k8], bf, acc01, 0, 0, 0);
            acc23 = __builtin_amdgcn_mfma_f32_32x32x16_bf16(afrag1[k8], bf, acc23, 0, 0, 0);
        }
        __builtin_amdgcn_s_setprio(0);
        // weighted relu reduce over heads; lane + lane^32 hold the 16 heads
        float p0 = 0.f, p1 = 0.f, p2 = 0.f, p3 = 0.f;
        #pragma unroll
        for (int r = 0; r < 8; ++r) {
            float a = acc01[r];     a = a > 0.f ? a : 0.f; p0 += w0r[r] * a;
            float b = acc01[r + 8]; b = b > 0.f ? b : 0.f; p1 += w1r[r] * b;
            float g = acc23[r];     g = g > 0.f ? g : 0.f; p2 += w2r[r] * g;
            float d = acc23[r + 8]; d = d > 0.f ? d : 0.f; p3 += w3r[r] * d;
        }
        p0 += __shfl_xor(p0, 32, 64);
        p1 += __shfl_xor(p1, 32, 64);
        p2 += __shfl_xor(p2, 32, 64);
        p3 += __shfl_xor(p3, 32, 64);
        const int s = kv0 + nrow;
        if (hi == 0) {
            if (v0 && s >= ks0 && s <= t0) scw[0][s - ks0] = p0;
            if (v2 && s >= ks2 && s <= t2) scw[2][s - ks2] = p2;
        } else {
            if (v1 && s >= ks1 && s <= t1) scw[1][s - ks1] = p1;
            if (v3 && s >= ks3 && s <= t3) scw[3][s - ks3] = p3;
        }
        __syncthreads();
    }

    // ---- select: wave wv owns token tt0+wv ----
    const int t_s = tt0 + wv;
    if (t_s >= T) return;
    const int ks_w = ks_of(seq_lens, n_seq, t_s);
    const int ke_w = t_s + 1;
    const int n    = ke_w - ks_w;

    const int nch = (n + 63) >> 6;
    uint32_t ukey[NCHT];
    #pragma unroll
    for (int c = 0; c < NCHT; ++c) {
        if (c < nch) {
            int i = c * 64 + lane;
            ukey[c] = (i < n) ? __float_as_uint(scw[wv][i]) : 0u;
        } else ukey[c] = 0u;
    }
    unsigned long long* candw = (unsigned long long*)&scw[wv][0];

    const int Keff = (n < K) ? n : K;
    uint32_t ustar = 0;
    int ttake = K;
    if (n > K) {
        uint32_t lo = 0, hia = 0x80000000u;
        for (int it = 0; it < 31; ++it) {
            uint32_t mid = (lo + hia) >> 1;
            int lc = 0;
            #pragma unroll
            for (int c = 0; c < NCHT; ++c)
                if (c < nch) lc += (ukey[c] >= mid) ? 1 : 0;
            int total = wave_reduce_add_dpp(lc);
            if (total >= K) lo = mid; else hia = mid;
        }
        ustar = lo;
        int lg = 0;
        #pragma unroll
        for (int c = 0; c < NCHT; ++c)
            if (c < nch) lg += (ukey[c] > ustar) ? 1 : 0;
        ttake = K - wave_reduce_add_dpp(lg);
    }

    // gather exactly Keff keys (ties by ascending index)
    {
        const unsigned long long ltm = (1ull << lane) - 1ull;
        int base = 0, tieBase = 0;
        const bool selAll = (n <= K);
        #pragma unroll
        for (int c = 0; c < NCHT; ++c) {
            if (c < nch) {
                int i = c * 64 + lane;
                bool inb = (i < n);
                uint32_t u = ukey[c];
                bool isGt  = inb && (selAll || u > ustar);
                bool isTie = inb && !selAll && (u == ustar);
                unsigned long long mt = __ballot(isTie);
                int tr = tieBase + (int)__popcll(mt & ltm);
                bool take = isGt || (isTie && tr < ttake);
                unsigned long long mk = __ballot(take);
                if (take) {
                    int pos = base + (int)__popcll(mk & ltm);
                    int s = ks_w + i;
                    if (pos < SORTN)
                        candw[pos] = ((((unsigned long long)u << 11) |
                                       (unsigned long long)(T - 1 - s)) + 1ull);
                }
                base    += (int)__popcll(mk);
                tieBase += (int)__popcll(mt);
            }
        }
        for (int i = Keff + lane; i < SORTN; i += 64) candw[i] = 0ull;
    }

    // register bitonic sort of 256 keys, descending; e = 4*lane + r
    unsigned long long kreg[4];
    #pragma unroll
    for (int r = 0; r < 4; ++r) kreg[r] = candw[4 * lane + r];

    #define CX(a, b, dsc) { unsigned long long _mx = (a) > (b) ? (a) : (b); \
                            unsigned long long _mn = (a) > (b) ? (b) : (a); \
                            (a) = (dsc) ? _mx : _mn; (b) = (dsc) ? _mn : _mx; }
    #pragma unroll
    for (int size = 2; size <= SORTN; size <<= 1) {
        #pragma unroll
        for (int stride = SORTN >> 1; stride >= 4; stride >>= 1) {
            if (stride > (size >> 1)) continue;
            int lmask = stride >> 2;
            #pragma unroll
            for (int r = 0; r < 4; ++r) {
                int e = 4 * lane + r;
                unsigned long long other = __shfl_xor(kreg[r], lmask, 64);
                bool desc = ((e & size) == 0);
                bool iAmLow = ((e & stride) == 0);
                bool keepMax = (iAmLow == desc);
                kreg[r] = keepMax ? (kreg[r] > other ? kreg[r] : other)
                                  : (kreg[r] < other ? kreg[r] : other);
            }
        }
        if (size >= 4) {
            bool d = (((4 * lane) & size) == 0);
            CX(kreg[0], kreg[2], d);
            CX(kreg[1], kreg[3], d);
            CX(kreg[0], kreg[1], d);
            CX(kreg[2], kreg[3], d);
        } else {
            CX(kreg[0], kreg[1], true);
            CX(kreg[2], kreg[3], false);
        }
    }
    #undef CX

    // ---- emit ----
    if (4 * lane < K) {
        float4_t v4, i4;
        #pragma unroll
        for (int r = 0; r < 4; ++r) {
            int e = 4 * lane + r;
            unsigned long long key = kreg[r];
            float v; int idx;
            if (key != 0ull) {
                unsigned long long km1 = key - 1ull;
                v = __uint_as_float((uint32_t)(km1 >> 11));
                idx = T - 1 - (int)(km1 & 0x7FFull);
            } else {
                int pidx = e - Keff;
                idx = (pidx < ks_w) ? pidx : (ke_w + (pidx - ks_w));
                v = -1e30f;
            }
            v4[r] = v; i4[r] = (float)idx;
        }
        *(float4_t*)(out_vals + (size_t)t_s * K + 4 * lane) = v4;
        *(float4_t*)(out_idx  + (size_t)t_s * K + 4 * lane) = i4;
    }
}

extern "C" void kernel_launch(void* const* d_in, const int* in_sizes, int n_in,
                              void* d_out, int out_size, void* d_ws, size_t ws_size,
                              hipStream_t stream) {
    const unsigned short* q = (const unsigned short*)d_in[0];
    const unsigned short* k = (const unsigned short*)d_in[1];
    const float* w          = (const float*)d_in[2];
    const int* seq_lens     = (const int*)d_in[3];
    const int n_seq = in_sizes[3];
    const int T = in_sizes[1] / DDIM;
    const int H = in_sizes[2] / T;
    const int K = out_size / (2 * T);

    unsigned short* kr = (unsigned short*)d_ws;   // [T,128] rotated k (512 KB)
    float* out_vals = (float*)d_out;
    float* out_idx  = out_vals + (size_t)T * K;

    rotate_k_kernel<<<dim3((T + 15) / 16), dim3(256), 0, stream>>>(k, kr, T);
    const int Tt = (T + 3) / 4;
    fused_kernel<<<dim3(Tt), dim3(256), 0, stream>>>(
        q, kr, w, seq_lens, n_seq, out_vals, out_idx, T, H, K, Tt);
}